// Round 1
// 1225.990 us; speedup vs baseline: 1.0374x; 1.0374x over previous
//
#include <hip/hip_runtime.h>
#include <stdint.h>

#define NN 20000
#define EE 640000
#define DDIM 128
#define D2 256
#define NLAY 3
#define BN_EPS 1e-5f

typedef short bf16x8 __attribute__((ext_vector_type(8)));
typedef float f32x4 __attribute__((ext_vector_type(4)));

__device__ __forceinline__ short f2bf(float f) {
    uint32_t u = __float_as_uint(f);
    u += 0x7fff + ((u >> 16) & 1);   // round-to-nearest-even
    return (short)(u >> 16);
}
__device__ __forceinline__ float bf2f(uint32_t u16) {
    return __uint_as_float(u16 << 16);
}

// ---------------- embedding ----------------
__global__ __launch_bounds__(256) void k_embed(const int* __restrict__ tok,
                                               const float* __restrict__ emb,
                                               float* __restrict__ h) {
    int gid = blockIdx.x * 256 + threadIdx.x;
    int r = gid >> 5;
    int c4 = gid & 31;
    int t = tok[r];
    ((float4*)h)[gid] = ((const float4*)emb)[t * 32 + c4];
}

// ---------------- counting sort of edges by dst ----------------
__global__ __launch_bounds__(256) void k_hist(const int* __restrict__ ei, int* __restrict__ counts) {
    int e = blockIdx.x * 256 + threadIdx.x;
    atomicAdd(&counts[ei[EE + e]], 1);
}

// coalesced single-block scan: stage counts in LDS, scan there, store coalesced
__global__ __launch_bounds__(1024) void k_scan(const int* __restrict__ counts, int* __restrict__ cursor) {
    __shared__ int buf[NN];        // 80000 B
    __shared__ int part[1024];
    int t = threadIdx.x;
    for (int i = t; i < NN; i += 1024) buf[i] = counts[i];
    __syncthreads();
    int base = t * 20;
    int s = 0;
    #pragma unroll
    for (int i = 0; i < 20; i++) {
        int idx = base + i;
        if (idx < NN) s += buf[idx];
    }
    part[t] = s;
    __syncthreads();
    for (int off = 1; off < 1024; off <<= 1) {
        int v = (t >= off) ? part[t - off] : 0;
        __syncthreads();
        part[t] += v;
        __syncthreads();
    }
    int run = part[t] - s;
    #pragma unroll
    for (int i = 0; i < 20; i++) {
        int idx = base + i;
        if (idx < NN) { int c = buf[idx]; buf[idx] = run; run += c; }
    }
    __syncthreads();
    for (int i = t; i < NN; i += 1024) cursor[i] = buf[i];
}

__global__ __launch_bounds__(256) void k_scatter(const int* __restrict__ ei,
                                                 int* __restrict__ cursor,
                                                 int* __restrict__ perm,
                                                 int* __restrict__ rank) {
    int e = blockIdx.x * 256 + threadIdx.x;
    int d = ei[EE + e];
    int pos = atomicAdd(&cursor[d], 1);
    perm[pos] = e;
    rank[e] = pos;
}

// ---------------- permute edge_attr into sorted order + bf16 ----
__global__ __launch_bounds__(256) void k_permute2(const float* __restrict__ edge_attr,
                                                  const int* __restrict__ ei,
                                                  const int* __restrict__ rank,
                                                  short* __restrict__ ea_bf,
                                                  int* __restrict__ srcs,
                                                  int* __restrict__ dsts) {
    int gid = blockIdx.x * 256 + threadIdx.x;   // 0..EE*32-1
    int e = gid >> 5, c4 = gid & 31;
    float4 v = ((const float4*)edge_attr)[gid];
    int pos = rank[e];
    short4 b;
    b.x = f2bf(v.x); b.y = f2bf(v.y); b.z = f2bf(v.z); b.w = f2bf(v.w);
    ((short4*)ea_bf)[(size_t)pos * 32 + c4] = b;
    if (c4 == 0) { srcs[pos] = ei[e]; dsts[pos] = ei[EE + e]; }
}

// ---------------- weight prep: transpose + fp32->bf16 ----------------
__global__ __launch_bounds__(256) void k_prepw(const float* __restrict__ src,
                                               short* __restrict__ dst,
                                               int K, int Nc, int total) {
    int gid = blockIdx.x * 256 + threadIdx.x;
    if (gid >= total) return;
    int per = K * Nc;
    int l = gid / per;
    int rem = gid - l * per;
    int k = rem / Nc;
    int n = rem - k * Nc;
    dst[(l * Nc + n) * K + k] = f2bf(src[gid]);
}

// ---------------- fused edge kernel (sorted bf16, inline lazy BN from stats) ----------------
__global__ __launch_bounds__(256) void k_edge3(const short* __restrict__ ea_bf,
                                               const int* __restrict__ srcs,
                                               const int* __restrict__ dsts,
                                               const short* __restrict__ WtL,
                                               const float* __restrict__ ebL,
                                               const float* __restrict__ hbase,
                                               const float* __restrict__ st2,
                                               const float* __restrict__ g2,
                                               const float* __restrict__ b2v,
                                               int lazy,
                                               float* __restrict__ agg) {
    __shared__ __align__(16) short sW[128 * 136];      // 34816 B
    __shared__ __align__(16) short sOutB[64 * 132];    // 16896 B (bf16 msg tile)
    __shared__ int sSrc[64], sDst[64];
    int tid = threadIdx.x;
    int tile = blockIdx.x;

    if (tid < 64) {
        sSrc[tid] = srcs[tile * 64 + tid];
        sDst[tid] = dsts[tile * 64 + tid];
    }
    // stage W (16384 bf16 = 4096 uint2)
    const uint2* wg = (const uint2*)WtL;
    #pragma unroll
    for (int i = 0; i < 16; i++) {
        int idx = tid + i * 256;
        uint2 v = wg[idx];
        int n = idx >> 5, k4 = (idx & 31) << 2;
        *(uint2*)&sW[n * 136 + k4] = v;
    }
    int lane = tid & 63, wv = tid >> 6;
    int l15 = lane & 15, quad = lane >> 4;
    int r0 = wv * 16;
    // A fragments straight from global (contiguous bf16 rows)
    const short* abase = ea_bf + ((size_t)(tile * 64 + r0 + l15)) * 128 + quad * 8;
    bf16x8 a[4];
    #pragma unroll
    for (int kt = 0; kt < 4; kt++) a[kt] = *(const bf16x8*)(abase + kt * 32);
    __syncthreads();   // sW + sSrc/sDst ready

    f32x4 acc[8];
    #pragma unroll
    for (int i = 0; i < 8; i++) acc[i] = (f32x4){0.f, 0.f, 0.f, 0.f};
    #pragma unroll
    for (int kt = 0; kt < 4; kt++) {
        #pragma unroll
        for (int nt = 0; nt < 8; nt++) {
            bf16x8 b = *(const bf16x8*)&sW[(nt * 16 + l15) * 136 + kt * 32 + quad * 8];
            acc[nt] = __builtin_amdgcn_mfma_f32_16x16x32_bf16(a[kt], b, acc[nt], 0, 0, 0);
        }
    }
    // epilogue: fold eb (column known here)
    #pragma unroll
    for (int nt = 0; nt < 8; nt++) {
        float ebv = ebL[nt * 16 + l15];
        #pragma unroll
        for (int reg = 0; reg < 4; reg++)
            sOutB[(r0 + quad * 4 + reg) * 132 + nt * 16 + l15] = f2bf(acc[nt][reg] + ebv);
    }
    __syncthreads();

    // parallel phase: msg = relu(geam+eb + BN2'(h[src])) — 16 independent iterations
    {
        int c2 = tid & 63;          // float2 column index (constant per thread)
        int c = c2 * 2;
        int rb = tid >> 6;          // 0..3
        float s0 = 0.f, s1 = 0.f, t0 = 0.f, t1 = 0.f;
        if (lazy) {                 // inline finalize of previous layer's BN2 stats
            float inv_n = 1.f / (float)NN;
            float mu0 = st2[c] * inv_n,     mu1 = st2[c + 1] * inv_n;
            float va0 = st2[128 + c] * inv_n - mu0 * mu0;
            float va1 = st2[129 + c] * inv_n - mu1 * mu1;
            s0 = g2[c] * rsqrtf(va0 + BN_EPS);     t0 = b2v[c] - mu0 * s0;
            s1 = g2[c + 1] * rsqrtf(va1 + BN_EPS); t1 = b2v[c + 1] - mu1 * s1;
        }
        #pragma unroll
        for (int i = 0; i < 16; i++) {
            int r = rb + i * 4;
            float2 hv = *(const float2*)&hbase[(size_t)sSrc[r] * DDIM + c];
            float h0, h1;
            if (lazy) {
                h0 = fmaxf(hv.x * s0 + t0, 0.f);
                h1 = fmaxf(hv.y * s1 + t1, 0.f);
            } else {
                h0 = hv.x; h1 = hv.y;
            }
            uint32_t pp = *(uint32_t*)&sOutB[r * 132 + c];
            float m0 = fmaxf(bf2f(pp & 0xffffu) + h0, 0.f);
            float m1 = fmaxf(bf2f(pp >> 16) + h1, 0.f);
            uint32_t po = (uint32_t)(uint16_t)f2bf(m0) | ((uint32_t)(uint16_t)f2bf(m1) << 16);
            *(uint32_t*)&sOutB[r * 132 + c] = po;
        }
    }
    __syncthreads();
    // serial segmented reduce over LDS only
    int c = tid & 127;
    int rbeg = (tid >> 7) * 32;
    float s = 0.f;
    int cur = sDst[rbeg];
    for (int r = rbeg; r < rbeg + 32; r++) {
        int d = sDst[r];
        if (d != cur) { atomicAdd(&agg[(size_t)cur * DDIM + c], s); s = 0.f; cur = d; }
        uint32_t raw = *(const uint16_t*)&sOutB[r * 132 + c];
        s += bf2f(raw);
    }
    atomicAdd(&agg[(size_t)cur * DDIM + c], s);
}

// ---------------- fallback edge kernel (gather, no lazy BN) ----------------
__global__ __launch_bounds__(256) void k_edge_g(const float* __restrict__ edge_attr,
                                                const short* __restrict__ WtL,
                                                const float* __restrict__ ebL,
                                                const float* __restrict__ h,
                                                const int* __restrict__ ei,
                                                const int* __restrict__ perm,
                                                float* __restrict__ agg) {
    __shared__ __align__(16) short sW[128 * 136];
    __shared__ __align__(16) char sU[64 * 132 * 4];
    __shared__ int sSrc[64], sDst[64], sEdge[64];
    short* sA = (short*)sU;
    float* sOut = (float*)sU;
    int tid = threadIdx.x;
    int tile = blockIdx.x;
    if (tid < 64) {
        int e = perm[tile * 64 + tid];
        sEdge[tid] = e;
        sSrc[tid] = ei[e];
        sDst[tid] = ei[EE + e];
    }
    const uint2* wg = (const uint2*)WtL;
    #pragma unroll
    for (int i = 0; i < 16; i++) {
        int idx = tid + i * 256;
        uint2 v = wg[idx];
        int n = idx >> 5, k4 = (idx & 31) << 2;
        *(uint2*)&sW[n * 136 + k4] = v;
    }
    __syncthreads();
    #pragma unroll
    for (int i = 0; i < 8; i++) {
        int idx = tid + i * 256;
        int r = idx >> 5, c4 = idx & 31;
        float4 v = ((const float4*)edge_attr)[sEdge[r] * 32 + c4];
        short4 b;
        b.x = f2bf(v.x); b.y = f2bf(v.y); b.z = f2bf(v.z); b.w = f2bf(v.w);
        *(short4*)&sA[r * 136 + (c4 << 2)] = b;
    }
    __syncthreads();
    int lane = tid & 63, wv = tid >> 6;
    int l15 = lane & 15, quad = lane >> 4;
    int r0 = wv * 16;
    f32x4 acc[8];
    #pragma unroll
    for (int i = 0; i < 8; i++) acc[i] = (f32x4){0.f, 0.f, 0.f, 0.f};
    #pragma unroll
    for (int kt = 0; kt < 4; kt++) {
        bf16x8 a = *(const bf16x8*)&sA[(r0 + l15) * 136 + kt * 32 + quad * 8];
        #pragma unroll
        for (int nt = 0; nt < 8; nt++) {
            bf16x8 b = *(const bf16x8*)&sW[(nt * 16 + l15) * 136 + kt * 32 + quad * 8];
            acc[nt] = __builtin_amdgcn_mfma_f32_16x16x32_bf16(a, b, acc[nt], 0, 0, 0);
        }
    }
    __syncthreads();
    #pragma unroll
    for (int nt = 0; nt < 8; nt++)
        #pragma unroll
        for (int reg = 0; reg < 4; reg++)
            sOut[(r0 + quad * 4 + reg) * 132 + nt * 16 + l15] = acc[nt][reg];
    __syncthreads();
    #pragma unroll
    for (int i = 0; i < 32; i++) {
        int idx = tid + i * 256;
        int r = idx >> 7, c = idx & 127;
        float v = sOut[r * 132 + c] + ebL[c] + h[(size_t)sSrc[r] * DDIM + c];
        sOut[r * 132 + c] = fmaxf(v, 0.f);
    }
    __syncthreads();
    int c = tid & 127;
    int rbeg = (tid >> 7) * 32;
    float s = 0.f;
    int cur = sDst[rbeg];
    for (int r = rbeg; r < rbeg + 32; r++) {
        int d = sDst[r];
        if (d != cur) { atomicAdd(&agg[(size_t)cur * DDIM + c], s); s = 0.f; cur = d; }
        s += sOut[r * 132 + c];
    }
    atomicAdd(&agg[(size_t)cur * DDIM + c], s);
}

// ---------------- GEMM1 (N-split halves) fused with z-computation, inline lazy BN2, BN1 stats ----
__global__ __launch_bounds__(256) void k_gemm1z(const float* __restrict__ hbase,
                                                const float* __restrict__ st2,
                                                const float* __restrict__ g2,
                                                const float* __restrict__ b2v,
                                                int lazy,
                                                const float* __restrict__ agg,
                                                const float* __restrict__ epsP, int l,
                                                const short* __restrict__ W1tL,
                                                float* __restrict__ zz,
                                                float* __restrict__ stats) {
    __shared__ __align__(16) short sB[128 * 136];  // 34816 B (half of W1)
    __shared__ __align__(16) short sA[64 * 136];   // 17408 B
    int tid = threadIdx.x;
    int tile = blockIdx.x;
    int half = blockIdx.y;
    float e1 = 1.f + epsP[l];
    const uint2* bg = (const uint2*)W1tL + (size_t)half * 128 * 32;
    #pragma unroll
    for (int i = 0; i < 16; i++) {
        int idx = tid + i * 256;
        uint2 v = bg[idx];
        int n = idx >> 5, k4 = (idx & 31) << 2;
        *(uint2*)&sB[n * 136 + k4] = v;
    }
    {
        int c4 = tid & 31;                 // constant per thread
        int c = c4 * 4;
        float scv[4] = {0.f, 0.f, 0.f, 0.f}, shv[4] = {0.f, 0.f, 0.f, 0.f};
        if (lazy) {                        // inline finalize of previous layer's BN2 stats
            float inv_n = 1.f / (float)NN;
            #pragma unroll
            for (int j = 0; j < 4; j++) {
                float mu = st2[c + j] * inv_n;
                float var = st2[128 + c + j] * inv_n - mu * mu;
                float sc = g2[c + j] * rsqrtf(var + BN_EPS);
                scv[j] = sc;
                shv[j] = b2v[c + j] - mu * sc;
            }
        }
        #pragma unroll
        for (int i = 0; i < 8; i++) {
            int idx = tid + i * 256;       // r = idx>>5 in 0..63
            int r = idx >> 5;
            int gr = tile * 64 + r;
            short4 o = {0, 0, 0, 0};
            if (gr < NN) {
                float4 hv = ((const float4*)hbase)[gr * 32 + c4];
                if (lazy) {
                    hv.x = fmaxf(hv.x * scv[0] + shv[0], 0.f);
                    hv.y = fmaxf(hv.y * scv[1] + shv[1], 0.f);
                    hv.z = fmaxf(hv.z * scv[2] + shv[2], 0.f);
                    hv.w = fmaxf(hv.w * scv[3] + shv[3], 0.f);
                }
                float4 av = ((const float4*)agg)[gr * 32 + c4];
                o.x = f2bf(e1 * hv.x + av.x);
                o.y = f2bf(e1 * hv.y + av.y);
                o.z = f2bf(e1 * hv.z + av.z);
                o.w = f2bf(e1 * hv.w + av.w);
            }
            *(short4*)&sA[r * 136 + c] = o;
        }
    }
    __syncthreads();
    int lane = tid & 63, wv = tid >> 6;
    int l15 = lane & 15, quad = lane >> 4;
    int r0 = wv * 16;
    f32x4 acc[8];
    #pragma unroll
    for (int i = 0; i < 8; i++) acc[i] = (f32x4){0.f, 0.f, 0.f, 0.f};
    #pragma unroll
    for (int kt = 0; kt < 4; kt++) {
        bf16x8 a = *(const bf16x8*)&sA[(r0 + l15) * 136 + kt * 32 + quad * 8];
        #pragma unroll
        for (int nt = 0; nt < 8; nt++) {
            bf16x8 b = *(const bf16x8*)&sB[(nt * 16 + l15) * 136 + kt * 32 + quad * 8];
            acc[nt] = __builtin_amdgcn_mfma_f32_16x16x32_bf16(a, b, acc[nt], 0, 0, 0);
        }
    }
    int grb = tile * 64 + r0 + quad * 4;
    #pragma unroll
    for (int nt = 0; nt < 8; nt++) {
        int col = half * 128 + nt * 16 + l15;
        float s = 0.f, s2 = 0.f;
        #pragma unroll
        for (int reg = 0; reg < 4; reg++) {
            int gr = grb + reg;
            float v = acc[nt][reg];
            s += v; s2 += v * v;
            if (gr < NN) zz[(size_t)gr * D2 + col] = v;
        }
        s += __shfl_xor(s, 16);  s += __shfl_xor(s, 32);
        s2 += __shfl_xor(s2, 16); s2 += __shfl_xor(s2, 32);
        if (quad == 0) {
            atomicAdd(&stats[col], s);
            atomicAdd(&stats[D2 + col], s2);
        }
    }
}

// ---------------- GEMM2 (N-split halves) fused with inline BN1 finalize + BN2 stats ----------------
__global__ __launch_bounds__(256) void k_gemm2s(const float* __restrict__ zz,
                                                const short* __restrict__ W2tL,
                                                const float* __restrict__ st1,
                                                const float* __restrict__ g1,
                                                const float* __restrict__ b1v,
                                                float* __restrict__ h_pre,
                                                float* __restrict__ stats) {
    __shared__ __align__(16) short sB[64 * 264];    // 33792 B (half of W2)
    __shared__ __align__(16) short sA[64 * 264];    // 33792 B
    __shared__ float sSc[256], sSh[256];
    int tid = threadIdx.x;
    int tile = blockIdx.x;
    int half = blockIdx.y;
    {   // inline finalize of BN1 stats (one col per thread)
        float inv_n = 1.f / (float)NN;
        float mu = st1[tid] * inv_n;
        float var = st1[256 + tid] * inv_n - mu * mu;
        float sc = g1[tid] * rsqrtf(var + BN_EPS);
        sSc[tid] = sc;
        sSh[tid] = b1v[tid] - mu * sc;
    }
    const uint2* bg = (const uint2*)W2tL + (size_t)half * 64 * 64;
    #pragma unroll
    for (int i = 0; i < 16; i++) {
        int idx = tid + i * 256;
        uint2 v = bg[idx];
        int n = idx >> 6, k4 = (idx & 63) << 2;
        *(uint2*)&sB[n * 264 + k4] = v;
    }
    __syncthreads();
    #pragma unroll
    for (int i = 0; i < 16; i++) {
        int idx = tid + i * 256;
        int r = idx >> 6, c4q = idx & 63;
        int c4 = c4q << 2;
        int gr = tile * 64 + r;
        short4 o = {0, 0, 0, 0};
        if (gr < NN) {
            float4 v = ((const float4*)zz)[gr * 64 + c4q];
            o.x = f2bf(fmaxf(v.x * sSc[c4 + 0] + sSh[c4 + 0], 0.f));
            o.y = f2bf(fmaxf(v.y * sSc[c4 + 1] + sSh[c4 + 1], 0.f));
            o.z = f2bf(fmaxf(v.z * sSc[c4 + 2] + sSh[c4 + 2], 0.f));
            o.w = f2bf(fmaxf(v.w * sSc[c4 + 3] + sSh[c4 + 3], 0.f));
        }
        *(short4*)&sA[r * 264 + c4] = o;
    }
    __syncthreads();
    int lane = tid & 63, wv = tid >> 6;
    int l15 = lane & 15, quad = lane >> 4;
    int r0 = wv * 16;
    f32x4 acc[4];
    #pragma unroll
    for (int i = 0; i < 4; i++) acc[i] = (f32x4){0.f, 0.f, 0.f, 0.f};
    #pragma unroll
    for (int kt = 0; kt < 8; kt++) {
        bf16x8 a = *(const bf16x8*)&sA[(r0 + l15) * 264 + kt * 32 + quad * 8];
        #pragma unroll
        for (int nt = 0; nt < 4; nt++) {
            bf16x8 b = *(const bf16x8*)&sB[(nt * 16 + l15) * 264 + kt * 32 + quad * 8];
            acc[nt] = __builtin_amdgcn_mfma_f32_16x16x32_bf16(a, b, acc[nt], 0, 0, 0);
        }
    }
    int grb = tile * 64 + r0 + quad * 4;
    #pragma unroll
    for (int nt = 0; nt < 4; nt++) {
        int col = half * 64 + nt * 16 + l15;
        float s = 0.f, s2 = 0.f;
        #pragma unroll
        for (int reg = 0; reg < 4; reg++) {
            int gr = grb + reg;
            float v = acc[nt][reg];
            s += v; s2 += v * v;
            if (gr < NN) h_pre[(size_t)gr * DDIM + col] = v;
        }
        s += __shfl_xor(s, 16);  s += __shfl_xor(s, 32);
        s2 += __shfl_xor(s2, 16); s2 += __shfl_xor(s2, 32);
        if (quad == 0) {
            atomicAdd(&stats[col], s);
            atomicAdd(&stats[DDIM + col], s2);
        }
    }
}

// ---------------- outer BN (+optional relu), inline finalize ----------------
__global__ __launch_bounds__(256) void k_bn2(const float* __restrict__ h_pre,
                                             const float* __restrict__ st2,
                                             const float* __restrict__ g2,
                                             const float* __restrict__ b2v,
                                             int do_relu, float* __restrict__ dst) {
    int gid = blockIdx.x * 256 + threadIdx.x;
    int c0 = (gid & 31) << 2;
    float inv_n = 1.f / (float)NN;
    float4 v = ((const float4*)h_pre)[gid];
    float o[4];
    #pragma unroll
    for (int j = 0; j < 4; j++) {
        float mu = st2[c0 + j] * inv_n;
        float var = st2[128 + c0 + j] * inv_n - mu * mu;
        float sc = g2[c0 + j] * rsqrtf(var + BN_EPS);
        float sh = b2v[c0 + j] - mu * sc;
        float x = (&v.x)[j] * sc + sh;
        o[j] = do_relu ? fmaxf(x, 0.f) : x;
    }
    float4 ov = make_float4(o[0], o[1], o[2], o[3]);
    ((float4*)dst)[gid] = ov;
}

extern "C" void kernel_launch(void* const* d_in, const int* in_sizes, int n_in,
                              void* d_out, int out_size, void* d_ws, size_t ws_size,
                              hipStream_t stream) {
    const int*   tok       = (const int*)d_in[0];
    const int*   ei        = (const int*)d_in[1];
    const float* edge_attr = (const float*)d_in[2];
    const float* emb       = (const float*)d_in[3];
    const float* eeW       = (const float*)d_in[4];
    const float* eeB       = (const float*)d_in[5];
    const float* W1        = (const float*)d_in[6];
    const float* bn1g      = (const float*)d_in[8];
    const float* bn1b      = (const float*)d_in[9];
    const float* W2        = (const float*)d_in[10];
    const float* epsP      = (const float*)d_in[12];
    const float* bng       = (const float*)d_in[13];
    const float* bnb       = (const float*)d_in[14];
    float* out = (float*)d_out;

    char* ws = (char*)d_ws;
    size_t off = 0;
    auto alloc = [&](size_t bytes) -> char* {
        off = (off + 511) & ~(size_t)511;
        char* p = ws + off;
        off += bytes;
        return p;
    };
    float* h      = (float*)alloc((size_t)NN * DDIM * 4);
    float* aggs   = (float*)alloc(((size_t)NN * DDIM + 512) * 4);  // agg + BN1 stats (contiguous for one memset)
    float* agg    = aggs;
    float* stats1 = aggs + (size_t)NN * DDIM;
    float* zz     = (float*)alloc((size_t)NN * D2 * 4);
    float* h_pre  = (float*)alloc((size_t)NN * DDIM * 4);
    int*   perm   = (int*)alloc((size_t)EE * 4);
    int*   rank   = (int*)alloc((size_t)EE * 4);
    int*   counts = (int*)alloc((size_t)NN * 4);
    int*   cursor = (int*)alloc((size_t)NN * 4);
    int*   srcs   = (int*)alloc((size_t)EE * 4);
    int*   dsts   = (int*)alloc((size_t)EE * 4);
    short* WtE    = (short*)alloc((size_t)NLAY * 128 * 128 * 2);
    short* W1t    = (short*)alloc((size_t)NLAY * 128 * 256 * 2);
    short* W2t    = (short*)alloc((size_t)NLAY * 256 * 128 * 2);
    float* stats2 = (float*)alloc(512 * 4);                        // ping-pong: 2 x 256
    short* ea_bf  = (short*)alloc((size_t)EE * DDIM * 2);          // 164 MB, allocated last
    bool big = (off <= ws_size);
    (void)in_sizes; (void)n_in; (void)out_size;

    hipMemsetAsync(counts, 0, (size_t)NN * 4, stream);
    {
        int t1 = NLAY * 128 * 128;
        k_prepw<<<(t1 + 255) / 256, 256, 0, stream>>>(eeW, WtE, 128, 128, t1);
        int t2 = NLAY * 128 * 256;
        k_prepw<<<(t2 + 255) / 256, 256, 0, stream>>>(W1, W1t, 128, 256, t2);
        int t3 = NLAY * 256 * 128;
        k_prepw<<<(t3 + 255) / 256, 256, 0, stream>>>(W2, W2t, 256, 128, t3);
    }
    k_embed<<<2500, 256, 0, stream>>>(tok, emb, h);
    k_hist<<<2500, 256, 0, stream>>>(ei, counts);
    k_scan<<<1, 1024, 0, stream>>>(counts, cursor);
    k_scatter<<<2500, 256, 0, stream>>>(ei, cursor, perm, rank);
    if (big) {
        k_permute2<<<EE * 32 / 256, 256, 0, stream>>>(edge_attr, ei, rank, ea_bf, srcs, dsts);
    }

    for (int l = 0; l < NLAY; l++) {
        hipMemsetAsync(aggs, 0, ((size_t)NN * DDIM + 512) * 4, stream);
        float* st2cur  = stats2 + (l & 1) * 256;
        float* st2prev = stats2 + ((l + 1) & 1) * 256;
        hipMemsetAsync(st2cur, 0, 256 * 4, stream);
        int lazy = (big && l > 0) ? 1 : 0;
        const float* hb  = lazy ? h_pre : h;
        int lp = (l > 0) ? (l - 1) : 0;
        const float* g2p = bng + (size_t)lp * 128;
        const float* b2p = bnb + (size_t)lp * 128;
        if (big) {
            k_edge3<<<EE / 64, 256, 0, stream>>>(ea_bf, srcs, dsts,
                                                 WtE + (size_t)l * 128 * 128,
                                                 eeB + (size_t)l * 128,
                                                 hb, st2prev, g2p, b2p, lazy, agg);
        } else {
            k_edge_g<<<EE / 64, 256, 0, stream>>>(edge_attr, WtE + (size_t)l * 128 * 128,
                                                  eeB + (size_t)l * 128, h, ei, perm, agg);
        }
        k_gemm1z<<<dim3((NN + 63) / 64, 2), 256, 0, stream>>>(hb, st2prev, g2p, b2p, lazy, agg,
                                                              epsP, l,
                                                              W1t + (size_t)l * 128 * 256, zz, stats1);
        k_gemm2s<<<dim3((NN + 63) / 64, 2), 256, 0, stream>>>(zz, W2t + (size_t)l * 256 * 128,
                                                              stats1, bn1g + (size_t)l * 256,
                                                              bn1b + (size_t)l * 256, h_pre, st2cur);
        if (big) {
            if (l == NLAY - 1)
                k_bn2<<<2500, 256, 0, stream>>>(h_pre, st2cur, bng + (size_t)l * 128,
                                                bnb + (size_t)l * 128, 0, out);
        } else {
            k_bn2<<<2500, 256, 0, stream>>>(h_pre, st2cur, bng + (size_t)l * 128,
                                            bnb + (size_t)l * 128, (l < NLAY - 1) ? 1 : 0,
                                            (l == NLAY - 1) ? out : h);
        }
    }
}

// Round 2
// 1179.085 us; speedup vs baseline: 1.0786x; 1.0398x over previous
//
#include <hip/hip_runtime.h>
#include <stdint.h>

#define NN 20000
#define EE 640000
#define DDIM 128
#define D2 256
#define NLAY 3
#define BN_EPS 1e-5f

typedef short bf16x8 __attribute__((ext_vector_type(8)));
typedef float f32x4 __attribute__((ext_vector_type(4)));

__device__ __forceinline__ short f2bf(float f) {
    uint32_t u = __float_as_uint(f);
    u += 0x7fff + ((u >> 16) & 1);   // round-to-nearest-even
    return (short)(u >> 16);
}
__device__ __forceinline__ float bf2f(uint32_t u16) {
    return __uint_as_float(u16 << 16);
}

// ---------------- embedding + dst histogram (fused: same 640000-thread shape) ----------------
__global__ __launch_bounds__(256) void k_embed_hist(const int* __restrict__ tok,
                                                    const float* __restrict__ emb,
                                                    float* __restrict__ h,
                                                    const int* __restrict__ ei,
                                                    int* __restrict__ counts) {
    int gid = blockIdx.x * 256 + threadIdx.x;     // 0..639999
    int r = gid >> 5;
    int c4 = gid & 31;
    int t = tok[r];
    ((float4*)h)[gid] = ((const float4*)emb)[t * 32 + c4];
    atomicAdd(&counts[ei[EE + gid]], 1);
}

// coalesced single-block scan: stage counts in LDS, scan there, store coalesced
__global__ __launch_bounds__(1024) void k_scan(const int* __restrict__ counts, int* __restrict__ cursor) {
    __shared__ int buf[NN];        // 80000 B
    __shared__ int part[1024];
    int t = threadIdx.x;
    for (int i = t; i < NN; i += 1024) buf[i] = counts[i];
    __syncthreads();
    int base = t * 20;
    int s = 0;
    #pragma unroll
    for (int i = 0; i < 20; i++) {
        int idx = base + i;
        if (idx < NN) s += buf[idx];
    }
    part[t] = s;
    __syncthreads();
    for (int off = 1; off < 1024; off <<= 1) {
        int v = (t >= off) ? part[t - off] : 0;
        __syncthreads();
        part[t] += v;
        __syncthreads();
    }
    int run = part[t] - s;
    #pragma unroll
    for (int i = 0; i < 20; i++) {
        int idx = base + i;
        if (idx < NN) { int c = buf[idx]; buf[idx] = run; run += c; }
    }
    __syncthreads();
    for (int i = t; i < NN; i += 1024) cursor[i] = buf[i];
}

__global__ __launch_bounds__(256) void k_scatter(const int* __restrict__ ei,
                                                 int* __restrict__ cursor,
                                                 int* __restrict__ perm,
                                                 int* __restrict__ rank) {
    int e = blockIdx.x * 256 + threadIdx.x;
    int d = ei[EE + e];
    int pos = atomicAdd(&cursor[d], 1);
    perm[pos] = e;
    rank[e] = pos;
}

// ---------------- permute edge_attr into sorted order + bf16 ----
__global__ __launch_bounds__(256) void k_permute2(const float* __restrict__ edge_attr,
                                                  const int* __restrict__ ei,
                                                  const int* __restrict__ rank,
                                                  short* __restrict__ ea_bf,
                                                  int* __restrict__ srcs,
                                                  int* __restrict__ dsts) {
    int gid = blockIdx.x * 256 + threadIdx.x;   // 0..EE*32-1
    int e = gid >> 5, c4 = gid & 31;
    float4 v = ((const float4*)edge_attr)[gid];
    int pos = rank[e];
    short4 b;
    b.x = f2bf(v.x); b.y = f2bf(v.y); b.z = f2bf(v.z); b.w = f2bf(v.w);
    ((short4*)ea_bf)[(size_t)pos * 32 + c4] = b;
    if (c4 == 0) { srcs[pos] = ei[e]; dsts[pos] = ei[EE + e]; }
}

// ---------------- weight prep (all three weights in one dispatch) ----------------
__global__ __launch_bounds__(256) void k_prepw_all(const float* __restrict__ eeW,
                                                   const float* __restrict__ W1,
                                                   const float* __restrict__ W2,
                                                   short* __restrict__ WtE,
                                                   short* __restrict__ W1t,
                                                   short* __restrict__ W2t) {
    int gid = blockIdx.x * 256 + threadIdx.x;
    const int T1 = NLAY * 128 * 128;     // 49152
    const int T2 = NLAY * 128 * 256;     // 98304
    const int T3 = NLAY * 256 * 128;     // 98304
    if (gid < T1) {
        int l = gid / (128 * 128), rem = gid % (128 * 128);
        int k = rem >> 7, n = rem & 127;
        WtE[(l * 128 + n) * 128 + k] = f2bf(eeW[gid]);
    } else if (gid < T1 + T2) {
        int g = gid - T1;
        int l = g / (128 * 256), rem = g % (128 * 256);
        int k = rem >> 8, n = rem & 255;
        W1t[(l * 256 + n) * 128 + k] = f2bf(W1[g]);
    } else if (gid < T1 + T2 + T3) {
        int g = gid - T1 - T2;
        int l = g / (256 * 128), rem = g % (256 * 128);
        int k = rem >> 7, n = rem & 127;
        W2t[(l * 128 + n) * 256 + k] = f2bf(W2[g]);
    }
}

// ---------------- fused edge kernel: 4 tiles/block (amortize W stage), inline lazy BN ----------------
__global__ __launch_bounds__(256) void k_edge3(const short* __restrict__ ea_bf,
                                               const int* __restrict__ srcs,
                                               const int* __restrict__ dsts,
                                               const short* __restrict__ WtL,
                                               const float* __restrict__ ebL,
                                               const float* __restrict__ hbase,
                                               const float* __restrict__ st2,
                                               const float* __restrict__ g2,
                                               const float* __restrict__ b2v,
                                               int lazy,
                                               float* __restrict__ agg) {
    __shared__ __align__(16) short sW[128 * 136];      // 34816 B
    __shared__ __align__(16) short sOutB[64 * 132];    // 16896 B (bf16 msg tile)
    __shared__ int sSrc[64], sDst[64];
    int tid = threadIdx.x;

    // stage W once per block (16384 bf16 = 4096 uint2)
    const uint2* wg = (const uint2*)WtL;
    #pragma unroll
    for (int i = 0; i < 16; i++) {
        int idx = tid + i * 256;
        uint2 v = wg[idx];
        int n = idx >> 5, k4 = (idx & 31) << 2;
        *(uint2*)&sW[n * 136 + k4] = v;
    }
    int lane = tid & 63, wv = tid >> 6;
    int l15 = lane & 15, quad = lane >> 4;
    int r0 = wv * 16;

    // hoisted epilogue bias (column fixed per thread)
    float ebv[8];
    #pragma unroll
    for (int nt = 0; nt < 8; nt++) ebv[nt] = ebL[nt * 16 + l15];

    // hoisted lazy-BN coefficients for the parallel phase (column fixed per thread)
    int pc2 = tid & 63;          // float2 column index
    int pc = pc2 * 2;
    int prb = tid >> 6;          // 0..3
    float ls0 = 0.f, ls1 = 0.f, lt0 = 0.f, lt1 = 0.f;
    if (lazy) {                  // inline finalize of previous layer's BN2 stats
        float inv_n = 1.f / (float)NN;
        float mu0 = st2[pc] * inv_n,     mu1 = st2[pc + 1] * inv_n;
        float va0 = st2[128 + pc] * inv_n - mu0 * mu0;
        float va1 = st2[129 + pc] * inv_n - mu1 * mu1;
        ls0 = g2[pc] * rsqrtf(va0 + BN_EPS);     lt0 = b2v[pc] - mu0 * ls0;
        ls1 = g2[pc + 1] * rsqrtf(va1 + BN_EPS); lt1 = b2v[pc + 1] - mu1 * ls1;
    }

    #pragma unroll 1
    for (int sub = 0; sub < 4; sub++) {
        int tile = blockIdx.x * 4 + sub;
        if (tid < 64) {
            sSrc[tid] = srcs[tile * 64 + tid];
            sDst[tid] = dsts[tile * 64 + tid];
        }
        // A fragments straight from global (contiguous bf16 rows)
        const short* abase = ea_bf + ((size_t)(tile * 64 + r0 + l15)) * 128 + quad * 8;
        bf16x8 a[4];
        #pragma unroll
        for (int kt = 0; kt < 4; kt++) a[kt] = *(const bf16x8*)(abase + kt * 32);
        if (sub == 0) __syncthreads();   // sW ready

        f32x4 acc[8];
        #pragma unroll
        for (int i = 0; i < 8; i++) acc[i] = (f32x4){0.f, 0.f, 0.f, 0.f};
        #pragma unroll
        for (int kt = 0; kt < 4; kt++) {
            #pragma unroll
            for (int nt = 0; nt < 8; nt++) {
                bf16x8 b = *(const bf16x8*)&sW[(nt * 16 + l15) * 136 + kt * 32 + quad * 8];
                acc[nt] = __builtin_amdgcn_mfma_f32_16x16x32_bf16(a[kt], b, acc[nt], 0, 0, 0);
            }
        }
        // epilogue: fold eb
        #pragma unroll
        for (int nt = 0; nt < 8; nt++) {
            #pragma unroll
            for (int reg = 0; reg < 4; reg++)
                sOutB[(r0 + quad * 4 + reg) * 132 + nt * 16 + l15] = f2bf(acc[nt][reg] + ebv[nt]);
        }
        __syncthreads();   // sOutB + sSrc/sDst visible

        // parallel phase: msg = relu(geam+eb + BN2'(h[src]))
        #pragma unroll
        for (int i = 0; i < 16; i++) {
            int r = prb + i * 4;
            float2 hv = *(const float2*)&hbase[(size_t)sSrc[r] * DDIM + pc];
            float h0, h1;
            if (lazy) {
                h0 = fmaxf(hv.x * ls0 + lt0, 0.f);
                h1 = fmaxf(hv.y * ls1 + lt1, 0.f);
            } else {
                h0 = hv.x; h1 = hv.y;
            }
            uint32_t pp = *(uint32_t*)&sOutB[r * 132 + pc];
            float m0 = fmaxf(bf2f(pp & 0xffffu) + h0, 0.f);
            float m1 = fmaxf(bf2f(pp >> 16) + h1, 0.f);
            uint32_t po = (uint32_t)(uint16_t)f2bf(m0) | ((uint32_t)(uint16_t)f2bf(m1) << 16);
            *(uint32_t*)&sOutB[r * 132 + pc] = po;
        }
        __syncthreads();
        // serial segmented reduce over LDS only
        int c = tid & 127;
        int rbeg = (tid >> 7) * 32;
        float s = 0.f;
        int cur = sDst[rbeg];
        for (int r = rbeg; r < rbeg + 32; r++) {
            int d = sDst[r];
            if (d != cur) { atomicAdd(&agg[(size_t)cur * DDIM + c], s); s = 0.f; cur = d; }
            uint32_t raw = *(const uint16_t*)&sOutB[r * 132 + c];
            s += bf2f(raw);
        }
        atomicAdd(&agg[(size_t)cur * DDIM + c], s);
        if (sub < 3) __syncthreads();    // free sSrc/sDst/sOutB for next sub
    }
}

// ---------------- fallback edge kernel (gather, no lazy BN) ----------------
__global__ __launch_bounds__(256) void k_edge_g(const float* __restrict__ edge_attr,
                                                const short* __restrict__ WtL,
                                                const float* __restrict__ ebL,
                                                const float* __restrict__ h,
                                                const int* __restrict__ ei,
                                                const int* __restrict__ perm,
                                                float* __restrict__ agg) {
    __shared__ __align__(16) short sW[128 * 136];
    __shared__ __align__(16) char sU[64 * 132 * 4];
    __shared__ int sSrc[64], sDst[64], sEdge[64];
    short* sA = (short*)sU;
    float* sOut = (float*)sU;
    int tid = threadIdx.x;
    int tile = blockIdx.x;
    if (tid < 64) {
        int e = perm[tile * 64 + tid];
        sEdge[tid] = e;
        sSrc[tid] = ei[e];
        sDst[tid] = ei[EE + e];
    }
    const uint2* wg = (const uint2*)WtL;
    #pragma unroll
    for (int i = 0; i < 16; i++) {
        int idx = tid + i * 256;
        uint2 v = wg[idx];
        int n = idx >> 5, k4 = (idx & 31) << 2;
        *(uint2*)&sW[n * 136 + k4] = v;
    }
    __syncthreads();
    #pragma unroll
    for (int i = 0; i < 8; i++) {
        int idx = tid + i * 256;
        int r = idx >> 5, c4 = idx & 31;
        float4 v = ((const float4*)edge_attr)[sEdge[r] * 32 + c4];
        short4 b;
        b.x = f2bf(v.x); b.y = f2bf(v.y); b.z = f2bf(v.z); b.w = f2bf(v.w);
        *(short4*)&sA[r * 136 + (c4 << 2)] = b;
    }
    __syncthreads();
    int lane = tid & 63, wv = tid >> 6;
    int l15 = lane & 15, quad = lane >> 4;
    int r0 = wv * 16;
    f32x4 acc[8];
    #pragma unroll
    for (int i = 0; i < 8; i++) acc[i] = (f32x4){0.f, 0.f, 0.f, 0.f};
    #pragma unroll
    for (int kt = 0; kt < 4; kt++) {
        bf16x8 a = *(const bf16x8*)&sA[(r0 + l15) * 136 + kt * 32 + quad * 8];
        #pragma unroll
        for (int nt = 0; nt < 8; nt++) {
            bf16x8 b = *(const bf16x8*)&sW[(nt * 16 + l15) * 136 + kt * 32 + quad * 8];
            acc[nt] = __builtin_amdgcn_mfma_f32_16x16x32_bf16(a, b, acc[nt], 0, 0, 0);
        }
    }
    __syncthreads();
    #pragma unroll
    for (int nt = 0; nt < 8; nt++)
        #pragma unroll
        for (int reg = 0; reg < 4; reg++)
            sOut[(r0 + quad * 4 + reg) * 132 + nt * 16 + l15] = acc[nt][reg];
    __syncthreads();
    #pragma unroll
    for (int i = 0; i < 32; i++) {
        int idx = tid + i * 256;
        int r = idx >> 7, c = idx & 127;
        float v = sOut[r * 132 + c] + ebL[c] + h[(size_t)sSrc[r] * DDIM + c];
        sOut[r * 132 + c] = fmaxf(v, 0.f);
    }
    __syncthreads();
    int c = tid & 127;
    int rbeg = (tid >> 7) * 32;
    float s = 0.f;
    int cur = sDst[rbeg];
    for (int r = rbeg; r < rbeg + 32; r++) {
        int d = sDst[r];
        if (d != cur) { atomicAdd(&agg[(size_t)cur * DDIM + c], s); s = 0.f; cur = d; }
        s += sOut[r * 132 + c];
    }
    atomicAdd(&agg[(size_t)cur * DDIM + c], s);
}

// ---------------- GEMM1 (N-split halves) fused with z-computation, inline lazy BN2, BN1 stats ----
__global__ __launch_bounds__(256) void k_gemm1z(const float* __restrict__ hbase,
                                                const float* __restrict__ st2,
                                                const float* __restrict__ g2,
                                                const float* __restrict__ b2v,
                                                int lazy,
                                                const float* __restrict__ agg,
                                                const float* __restrict__ epsP, int l,
                                                const short* __restrict__ W1tL,
                                                float* __restrict__ zz,
                                                float* __restrict__ stats) {
    __shared__ __align__(16) short sB[128 * 136];  // 34816 B (half of W1)
    __shared__ __align__(16) short sA[64 * 136];   // 17408 B
    int tid = threadIdx.x;
    int tile = blockIdx.x;
    int half = blockIdx.y;
    float e1 = 1.f + epsP[l];
    const uint2* bg = (const uint2*)W1tL + (size_t)half * 128 * 32;
    #pragma unroll
    for (int i = 0; i < 16; i++) {
        int idx = tid + i * 256;
        uint2 v = bg[idx];
        int n = idx >> 5, k4 = (idx & 31) << 2;
        *(uint2*)&sB[n * 136 + k4] = v;
    }
    {
        int c4 = tid & 31;                 // constant per thread
        int c = c4 * 4;
        float scv[4] = {0.f, 0.f, 0.f, 0.f}, shv[4] = {0.f, 0.f, 0.f, 0.f};
        if (lazy) {                        // inline finalize of previous layer's BN2 stats
            float inv_n = 1.f / (float)NN;
            #pragma unroll
            for (int j = 0; j < 4; j++) {
                float mu = st2[c + j] * inv_n;
                float var = st2[128 + c + j] * inv_n - mu * mu;
                float sc = g2[c + j] * rsqrtf(var + BN_EPS);
                scv[j] = sc;
                shv[j] = b2v[c + j] - mu * sc;
            }
        }
        #pragma unroll
        for (int i = 0; i < 8; i++) {
            int idx = tid + i * 256;       // r = idx>>5 in 0..63
            int r = idx >> 5;
            int gr = tile * 64 + r;
            short4 o = {0, 0, 0, 0};
            if (gr < NN) {
                float4 hv = ((const float4*)hbase)[gr * 32 + c4];
                if (lazy) {
                    hv.x = fmaxf(hv.x * scv[0] + shv[0], 0.f);
                    hv.y = fmaxf(hv.y * scv[1] + shv[1], 0.f);
                    hv.z = fmaxf(hv.z * scv[2] + shv[2], 0.f);
                    hv.w = fmaxf(hv.w * scv[3] + shv[3], 0.f);
                }
                float4 av = ((const float4*)agg)[gr * 32 + c4];
                o.x = f2bf(e1 * hv.x + av.x);
                o.y = f2bf(e1 * hv.y + av.y);
                o.z = f2bf(e1 * hv.z + av.z);
                o.w = f2bf(e1 * hv.w + av.w);
            }
            *(short4*)&sA[r * 136 + c] = o;
        }
    }
    __syncthreads();
    int lane = tid & 63, wv = tid >> 6;
    int l15 = lane & 15, quad = lane >> 4;
    int r0 = wv * 16;
    f32x4 acc[8];
    #pragma unroll
    for (int i = 0; i < 8; i++) acc[i] = (f32x4){0.f, 0.f, 0.f, 0.f};
    #pragma unroll
    for (int kt = 0; kt < 4; kt++) {
        bf16x8 a = *(const bf16x8*)&sA[(r0 + l15) * 136 + kt * 32 + quad * 8];
        #pragma unroll
        for (int nt = 0; nt < 8; nt++) {
            bf16x8 b = *(const bf16x8*)&sB[(nt * 16 + l15) * 136 + kt * 32 + quad * 8];
            acc[nt] = __builtin_amdgcn_mfma_f32_16x16x32_bf16(a, b, acc[nt], 0, 0, 0);
        }
    }
    int grb = tile * 64 + r0 + quad * 4;
    #pragma unroll
    for (int nt = 0; nt < 8; nt++) {
        int col = half * 128 + nt * 16 + l15;
        float s = 0.f, s2 = 0.f;
        #pragma unroll
        for (int reg = 0; reg < 4; reg++) {
            int gr = grb + reg;
            float v = acc[nt][reg];
            s += v; s2 += v * v;
            if (gr < NN) zz[(size_t)gr * D2 + col] = v;
        }
        s += __shfl_xor(s, 16);  s += __shfl_xor(s, 32);
        s2 += __shfl_xor(s2, 16); s2 += __shfl_xor(s2, 32);
        if (quad == 0) {
            atomicAdd(&stats[col], s);
            atomicAdd(&stats[D2 + col], s2);
        }
    }
}

// ---------------- GEMM2 (N-split halves, K-split staging) with inline BN1 finalize + BN2 stats ----
__global__ __launch_bounds__(256) void k_gemm2s(const float* __restrict__ zz,
                                                const short* __restrict__ W2tL,
                                                const float* __restrict__ st1,
                                                const float* __restrict__ g1,
                                                const float* __restrict__ b1v,
                                                float* __restrict__ h_pre,
                                                float* __restrict__ stats) {
    __shared__ __align__(16) short sB[64 * 136];    // 17408 B (N-half, K-half of W2)
    __shared__ __align__(16) short sA[64 * 136];    // 17408 B
    __shared__ float sSc[256], sSh[256];
    int tid = threadIdx.x;
    int tile = blockIdx.x;
    int half = blockIdx.y;
    int lane = tid & 63, wv = tid >> 6;
    int l15 = lane & 15, quad = lane >> 4;
    int r0 = wv * 16;
    f32x4 acc[4];
    #pragma unroll
    for (int i = 0; i < 4; i++) acc[i] = (f32x4){0.f, 0.f, 0.f, 0.f};

    #pragma unroll 1
    for (int p = 0; p < 2; p++) {
        if (p == 0) {
            // inline finalize of BN1 stats (one col per thread)
            float inv_n = 1.f / (float)NN;
            float mu = st1[tid] * inv_n;
            float var = st1[256 + tid] * inv_n - mu * mu;
            float sc = g1[tid] * rsqrtf(var + BN_EPS);
            sSc[tid] = sc;
            sSh[tid] = b1v[tid] - mu * sc;
            // stage B K-half 0 (doesn't need sSc)
            const uint2* bg = (const uint2*)W2tL + (size_t)half * 64 * 64;
            #pragma unroll
            for (int i = 0; i < 8; i++) {
                int idx = tid + i * 256;
                int n = idx >> 5, k4q = idx & 31;
                uint2 v = bg[n * 64 + k4q];
                *(uint2*)&sB[n * 136 + k4q * 4] = v;
            }
            __syncthreads();      // sSc visible for A-stage
        } else {
            __syncthreads();      // free sA/sB after MFMA phase 0
            const uint2* bg = (const uint2*)W2tL + (size_t)half * 64 * 64 + 32;
            #pragma unroll
            for (int i = 0; i < 8; i++) {
                int idx = tid + i * 256;
                int n = idx >> 5, k4q = idx & 31;
                uint2 v = bg[n * 64 + k4q];
                *(uint2*)&sB[n * 136 + k4q * 4] = v;
            }
        }
        // stage A K-half p: cols p*128 .. p*128+127 of zz, with BN1+relu applied
        {
            int c4q = tid & 31;
            int cb = p * 128 + c4q * 4;
            #pragma unroll
            for (int i = 0; i < 8; i++) {
                int r = (tid >> 5) + i * 8;
                int gr = tile * 64 + r;
                short4 o = {0, 0, 0, 0};
                if (gr < NN) {
                    float4 v = ((const float4*)zz)[(size_t)gr * 64 + p * 32 + c4q];
                    o.x = f2bf(fmaxf(v.x * sSc[cb + 0] + sSh[cb + 0], 0.f));
                    o.y = f2bf(fmaxf(v.y * sSc[cb + 1] + sSh[cb + 1], 0.f));
                    o.z = f2bf(fmaxf(v.z * sSc[cb + 2] + sSh[cb + 2], 0.f));
                    o.w = f2bf(fmaxf(v.w * sSc[cb + 3] + sSh[cb + 3], 0.f));
                }
                *(short4*)&sA[r * 136 + c4q * 4] = o;
            }
        }
        __syncthreads();    // sA+sB ready
        #pragma unroll
        for (int kt = 0; kt < 4; kt++) {
            bf16x8 a = *(const bf16x8*)&sA[(r0 + l15) * 136 + kt * 32 + quad * 8];
            #pragma unroll
            for (int nt = 0; nt < 4; nt++) {
                bf16x8 b = *(const bf16x8*)&sB[(nt * 16 + l15) * 136 + kt * 32 + quad * 8];
                acc[nt] = __builtin_amdgcn_mfma_f32_16x16x32_bf16(a, b, acc[nt], 0, 0, 0);
            }
        }
    }
    int grb = tile * 64 + r0 + quad * 4;
    #pragma unroll
    for (int nt = 0; nt < 4; nt++) {
        int col = half * 64 + nt * 16 + l15;
        float s = 0.f, s2 = 0.f;
        #pragma unroll
        for (int reg = 0; reg < 4; reg++) {
            int gr = grb + reg;
            float v = acc[nt][reg];
            s += v; s2 += v * v;
            if (gr < NN) h_pre[(size_t)gr * DDIM + col] = v;
        }
        s += __shfl_xor(s, 16);  s += __shfl_xor(s, 32);
        s2 += __shfl_xor(s2, 16); s2 += __shfl_xor(s2, 32);
        if (quad == 0) {
            atomicAdd(&stats[col], s);
            atomicAdd(&stats[DDIM + col], s2);
        }
    }
}

// ---------------- outer BN (+optional relu), inline finalize ----------------
__global__ __launch_bounds__(256) void k_bn2(const float* __restrict__ h_pre,
                                             const float* __restrict__ st2,
                                             const float* __restrict__ g2,
                                             const float* __restrict__ b2v,
                                             int do_relu, float* __restrict__ dst) {
    int gid = blockIdx.x * 256 + threadIdx.x;
    int c0 = (gid & 31) << 2;
    float inv_n = 1.f / (float)NN;
    float4 v = ((const float4*)h_pre)[gid];
    float o[4];
    #pragma unroll
    for (int j = 0; j < 4; j++) {
        float mu = st2[c0 + j] * inv_n;
        float var = st2[128 + c0 + j] * inv_n - mu * mu;
        float sc = g2[c0 + j] * rsqrtf(var + BN_EPS);
        float sh = b2v[c0 + j] - mu * sc;
        float x = (&v.x)[j] * sc + sh;
        o[j] = do_relu ? fmaxf(x, 0.f) : x;
    }
    float4 ov = make_float4(o[0], o[1], o[2], o[3]);
    ((float4*)dst)[gid] = ov;
}

extern "C" void kernel_launch(void* const* d_in, const int* in_sizes, int n_in,
                              void* d_out, int out_size, void* d_ws, size_t ws_size,
                              hipStream_t stream) {
    const int*   tok       = (const int*)d_in[0];
    const int*   ei        = (const int*)d_in[1];
    const float* edge_attr = (const float*)d_in[2];
    const float* emb       = (const float*)d_in[3];
    const float* eeW       = (const float*)d_in[4];
    const float* eeB       = (const float*)d_in[5];
    const float* W1        = (const float*)d_in[6];
    const float* bn1g      = (const float*)d_in[8];
    const float* bn1b      = (const float*)d_in[9];
    const float* W2        = (const float*)d_in[10];
    const float* epsP      = (const float*)d_in[12];
    const float* bng       = (const float*)d_in[13];
    const float* bnb       = (const float*)d_in[14];
    float* out = (float*)d_out;

    char* ws = (char*)d_ws;
    size_t off = 0;
    auto alloc = [&](size_t bytes) -> char* {
        off = (off + 511) & ~(size_t)511;
        char* p = ws + off;
        off += bytes;
        return p;
    };
    float* h      = (float*)alloc((size_t)NN * DDIM * 4);
    float* aggs   = (float*)alloc(((size_t)NN * DDIM + 512) * 4);  // agg + BN1 stats (one memset)
    float* agg    = aggs;
    float* stats1 = aggs + (size_t)NN * DDIM;
    float* zz     = (float*)alloc((size_t)NN * D2 * 4);
    float* h_pre  = (float*)alloc((size_t)NN * DDIM * 4);
    int*   perm   = (int*)alloc((size_t)EE * 4);
    int*   rank   = (int*)alloc((size_t)EE * 4);
    int*   counts = (int*)alloc((size_t)NN * 4);
    int*   cursor = (int*)alloc((size_t)NN * 4);
    int*   srcs   = (int*)alloc((size_t)EE * 4);
    int*   dsts   = (int*)alloc((size_t)EE * 4);
    short* WtE    = (short*)alloc((size_t)NLAY * 128 * 128 * 2);
    short* W1t    = (short*)alloc((size_t)NLAY * 128 * 256 * 2);
    short* W2t    = (short*)alloc((size_t)NLAY * 256 * 128 * 2);
    float* stats2 = (float*)alloc(512 * 4);                        // ping-pong: 2 x 256
    short* ea_bf  = (short*)alloc((size_t)EE * DDIM * 2);          // 164 MB, allocated last
    bool big = (off <= ws_size);
    (void)in_sizes; (void)n_in; (void)out_size;

    hipMemsetAsync(counts, 0, (size_t)NN * 4, stream);
    k_prepw_all<<<960, 256, 0, stream>>>(eeW, W1, W2, WtE, W1t, W2t);
    k_embed_hist<<<2500, 256, 0, stream>>>(tok, emb, h, ei, counts);
    k_scan<<<1, 1024, 0, stream>>>(counts, cursor);
    k_scatter<<<2500, 256, 0, stream>>>(ei, cursor, perm, rank);
    if (big) {
        k_permute2<<<EE * 32 / 256, 256, 0, stream>>>(edge_attr, ei, rank, ea_bf, srcs, dsts);
    }

    for (int l = 0; l < NLAY; l++) {
        hipMemsetAsync(aggs, 0, ((size_t)NN * DDIM + 512) * 4, stream);
        float* st2cur  = stats2 + (l & 1) * 256;
        float* st2prev = stats2 + ((l + 1) & 1) * 256;
        hipMemsetAsync(st2cur, 0, 256 * 4, stream);
        int lazy = (big && l > 0) ? 1 : 0;
        const float* hb  = lazy ? h_pre : h;
        int lp = (l > 0) ? (l - 1) : 0;
        const float* g2p = bng + (size_t)lp * 128;
        const float* b2p = bnb + (size_t)lp * 128;
        if (big) {
            k_edge3<<<EE / 256, 256, 0, stream>>>(ea_bf, srcs, dsts,
                                                  WtE + (size_t)l * 128 * 128,
                                                  eeB + (size_t)l * 128,
                                                  hb, st2prev, g2p, b2p, lazy, agg);
        } else {
            k_edge_g<<<EE / 64, 256, 0, stream>>>(edge_attr, WtE + (size_t)l * 128 * 128,
                                                  eeB + (size_t)l * 128, h, ei, perm, agg);
        }
        k_gemm1z<<<dim3((NN + 63) / 64, 2), 256, 0, stream>>>(hb, st2prev, g2p, b2p, lazy, agg,
                                                              epsP, l,
                                                              W1t + (size_t)l * 128 * 256, zz, stats1);
        k_gemm2s<<<dim3((NN + 63) / 64, 2), 256, 0, stream>>>(zz, W2t + (size_t)l * 256 * 128,
                                                              stats1, bn1g + (size_t)l * 256,
                                                              bn1b + (size_t)l * 256, h_pre, st2cur);
        if (big) {
            if (l == NLAY - 1)
                k_bn2<<<2500, 256, 0, stream>>>(h_pre, st2cur, bng + (size_t)l * 128,
                                                bnb + (size_t)l * 128, 0, out);
        } else {
            k_bn2<<<2500, 256, 0, stream>>>(h_pre, st2cur, bng + (size_t)l * 128,
                                            bnb + (size_t)l * 128, (l < NLAY - 1) ? 1 : 0,
                                            (l == NLAY - 1) ? out : h);
        }
    }
}

// Round 3
// 1172.942 us; speedup vs baseline: 1.0843x; 1.0052x over previous
//
#include <hip/hip_runtime.h>
#include <stdint.h>

#define NN 20000
#define EE 640000
#define DDIM 128
#define D2 256
#define NLAY 3
#define BN_EPS 1e-5f
#define SUBS 8

typedef short bf16x8 __attribute__((ext_vector_type(8)));
typedef float f32x4 __attribute__((ext_vector_type(4)));

__device__ __forceinline__ short f2bf(float f) {
    uint32_t u = __float_as_uint(f);
    u += 0x7fff + ((u >> 16) & 1);   // round-to-nearest-even
    return (short)(u >> 16);
}
__device__ __forceinline__ float bf2f(uint32_t u16) {
    return __uint_as_float(u16 << 16);
}

// ---------------- embedding (bf16 out) + dst histogram ----------------
__global__ __launch_bounds__(256) void k_embed_hist(const int* __restrict__ tok,
                                                    const float* __restrict__ emb,
                                                    short* __restrict__ h_bn,
                                                    const int* __restrict__ ei,
                                                    int* __restrict__ counts) {
    int gid = blockIdx.x * 256 + threadIdx.x;     // 0..639999
    int r = gid >> 5;
    int c4 = gid & 31;
    int t = tok[r];
    float4 e = ((const float4*)emb)[t * 32 + c4];
    short4 o;
    o.x = f2bf(e.x); o.y = f2bf(e.y); o.z = f2bf(e.z); o.w = f2bf(e.w);
    ((short4*)h_bn)[gid] = o;
    atomicAdd(&counts[ei[EE + gid]], 1);
}

// coalesced single-block scan
__global__ __launch_bounds__(1024) void k_scan(const int* __restrict__ counts, int* __restrict__ cursor) {
    __shared__ int buf[NN];        // 80000 B
    __shared__ int part[1024];
    int t = threadIdx.x;
    for (int i = t; i < NN; i += 1024) buf[i] = counts[i];
    __syncthreads();
    int base = t * 20;
    int s = 0;
    #pragma unroll
    for (int i = 0; i < 20; i++) {
        int idx = base + i;
        if (idx < NN) s += buf[idx];
    }
    part[t] = s;
    __syncthreads();
    for (int off = 1; off < 1024; off <<= 1) {
        int v = (t >= off) ? part[t - off] : 0;
        __syncthreads();
        part[t] += v;
        __syncthreads();
    }
    int run = part[t] - s;
    #pragma unroll
    for (int i = 0; i < 20; i++) {
        int idx = base + i;
        if (idx < NN) { int c = buf[idx]; buf[idx] = run; run += c; }
    }
    __syncthreads();
    for (int i = t; i < NN; i += 1024) cursor[i] = buf[i];
}

__global__ __launch_bounds__(256) void k_scatter(const int* __restrict__ ei,
                                                 int* __restrict__ cursor,
                                                 int* __restrict__ perm,
                                                 int* __restrict__ rank) {
    int e = blockIdx.x * 256 + threadIdx.x;
    int d = ei[EE + e];
    int pos = atomicAdd(&cursor[d], 1);
    perm[pos] = e;
    rank[e] = pos;
}

// ---------------- permute edge_attr into sorted order + bf16 ----
__global__ __launch_bounds__(256) void k_permute2(const float* __restrict__ edge_attr,
                                                  const int* __restrict__ ei,
                                                  const int* __restrict__ rank,
                                                  short* __restrict__ ea_bf,
                                                  int* __restrict__ srcs,
                                                  int* __restrict__ dsts) {
    int gid = blockIdx.x * 256 + threadIdx.x;   // 0..EE*32-1
    int e = gid >> 5, c4 = gid & 31;
    float4 v = ((const float4*)edge_attr)[gid];
    int pos = rank[e];
    short4 b;
    b.x = f2bf(v.x); b.y = f2bf(v.y); b.z = f2bf(v.z); b.w = f2bf(v.w);
    ((short4*)ea_bf)[(size_t)pos * 32 + c4] = b;
    if (c4 == 0) { srcs[pos] = ei[e]; dsts[pos] = ei[EE + e]; }
}

// ---------------- weight prep (all three weights in one dispatch) ----------------
__global__ __launch_bounds__(256) void k_prepw_all(const float* __restrict__ eeW,
                                                   const float* __restrict__ W1,
                                                   const float* __restrict__ W2,
                                                   short* __restrict__ WtE,
                                                   short* __restrict__ W1t,
                                                   short* __restrict__ W2t) {
    int gid = blockIdx.x * 256 + threadIdx.x;
    const int T1 = NLAY * 128 * 128;     // 49152
    const int T2 = NLAY * 128 * 256;     // 98304
    const int T3 = NLAY * 256 * 128;     // 98304
    if (gid < T1) {
        int l = gid / (128 * 128), rem = gid % (128 * 128);
        int k = rem >> 7, n = rem & 127;
        WtE[(l * 128 + n) * 128 + k] = f2bf(eeW[gid]);
    } else if (gid < T1 + T2) {
        int g = gid - T1;
        int l = g / (128 * 256), rem = g % (128 * 256);
        int k = rem >> 8, n = rem & 255;
        W1t[(l * 256 + n) * 128 + k] = f2bf(W1[g]);
    } else if (gid < T1 + T2 + T3) {
        int g = gid - T1 - T2;
        int l = g / (256 * 128), rem = g % (256 * 128);
        int k = rem >> 7, n = rem & 127;
        W2t[(l * 128 + n) * 256 + k] = f2bf(W2[g]);
    }
}

// ---------------- fused edge kernel: 8 tiles/block, prefetch-pipelined, bf16 h ----------------
__global__ __launch_bounds__(256) void k_edge3(const short* __restrict__ ea_bf,
                                               const int* __restrict__ srcs,
                                               const int* __restrict__ dsts,
                                               const short* __restrict__ WtL,
                                               const float* __restrict__ ebL,
                                               const short* __restrict__ h_bn,
                                               float* __restrict__ agg) {
    __shared__ __align__(16) short sW[128 * 136];      // 34816 B
    __shared__ __align__(16) short sOutB[64 * 132];    // 16896 B
    __shared__ int sSrc[2][64], sDst[2][64];
    int tid = threadIdx.x;
    int tile0 = blockIdx.x * SUBS;

    // stage W once per block
    const uint2* wg = (const uint2*)WtL;
    #pragma unroll
    for (int i = 0; i < 16; i++) {
        int idx = tid + i * 256;
        uint2 v = wg[idx];
        int n = idx >> 5, k4 = (idx & 31) << 2;
        *(uint2*)&sW[n * 136 + k4] = v;
    }
    int lane = tid & 63, wv = tid >> 6;
    int l15 = lane & 15, quad = lane >> 4;
    int r0 = wv * 16;
    float ebv[8];
    #pragma unroll
    for (int nt = 0; nt < 8; nt++) ebv[nt] = ebL[nt * 16 + l15];
    int pc = (tid & 63) * 2;     // bf16 column pair per thread
    int prb = tid >> 6;          // 0..3

    // prologue: first tile's src/dst + A fragments
    if (tid < 64) {
        sSrc[0][tid] = srcs[tile0 * 64 + tid];
        sDst[0][tid] = dsts[tile0 * 64 + tid];
    }
    const short* abase = ea_bf + ((size_t)tile0 * 64 + r0 + l15) * 128 + quad * 8;
    bf16x8 a[4];
    #pragma unroll
    for (int kt = 0; kt < 4; kt++) a[kt] = *(const bf16x8*)(abase + kt * 32);
    __syncthreads();   // sW + buf0 ready

    #pragma unroll 1
    for (int sub = 0; sub < SUBS; sub++) {
        int buf = sub & 1;
        f32x4 acc[8];
        #pragma unroll
        for (int i = 0; i < 8; i++) acc[i] = (f32x4){0.f, 0.f, 0.f, 0.f};
        #pragma unroll
        for (int kt = 0; kt < 4; kt++) {
            #pragma unroll
            for (int nt = 0; nt < 8; nt++) {
                bf16x8 b = *(const bf16x8*)&sW[(nt * 16 + l15) * 136 + kt * 32 + quad * 8];
                acc[nt] = __builtin_amdgcn_mfma_f32_16x16x32_bf16(a[kt], b, acc[nt], 0, 0, 0);
            }
        }
        // prefetch next sub (hide global latency under epilogue+gather+reduce)
        bf16x8 an[4];
        if (sub + 1 < SUBS) {
            const short* nb = abase + (size_t)(sub + 1) * 64 * 128;
            #pragma unroll
            for (int kt = 0; kt < 4; kt++) an[kt] = *(const bf16x8*)(nb + kt * 32);
            if (tid < 64) {
                sSrc[buf ^ 1][tid] = srcs[(tile0 + sub + 1) * 64 + tid];
                sDst[buf ^ 1][tid] = dsts[(tile0 + sub + 1) * 64 + tid];
            }
        }
        // epilogue: fold eb, write bf16 msg tile
        #pragma unroll
        for (int nt = 0; nt < 8; nt++) {
            #pragma unroll
            for (int reg = 0; reg < 4; reg++)
                sOutB[(r0 + quad * 4 + reg) * 132 + nt * 16 + l15] = f2bf(acc[nt][reg] + ebv[nt]);
        }
        __syncthreads();   // sOutB visible

        // gather phase: msg = relu(geam+eb + h_bn[src]) — wave reads 256 B/row coalesced
        #pragma unroll
        for (int i = 0; i < 16; i++) {
            int r = prb + i * 4;
            uint32_t hb = *(const uint32_t*)&h_bn[(size_t)sSrc[buf][r] * DDIM + pc];
            uint32_t pp = *(uint32_t*)&sOutB[r * 132 + pc];
            float m0 = fmaxf(bf2f(pp & 0xffffu) + bf2f(hb & 0xffffu), 0.f);
            float m1 = fmaxf(bf2f(pp >> 16) + bf2f(hb >> 16), 0.f);
            uint32_t po = (uint32_t)(uint16_t)f2bf(m0) | ((uint32_t)(uint16_t)f2bf(m1) << 16);
            *(uint32_t*)&sOutB[r * 132 + pc] = po;
        }
        __syncthreads();
        // serial segmented reduce over LDS only
        int c = tid & 127;
        int rbeg = (tid >> 7) * 32;
        float s = 0.f;
        int cur = sDst[buf][rbeg];
        for (int r = rbeg; r < rbeg + 32; r++) {
            int d = sDst[buf][r];
            if (d != cur) { atomicAdd(&agg[(size_t)cur * DDIM + c], s); s = 0.f; cur = d; }
            s += bf2f(*(const uint16_t*)&sOutB[r * 132 + c]);
        }
        atomicAdd(&agg[(size_t)cur * DDIM + c], s);
        if (sub + 1 < SUBS) {
            #pragma unroll
            for (int kt = 0; kt < 4; kt++) a[kt] = an[kt];
            __syncthreads();    // free sOutB + order sSrc/sDst buf writes
        }
    }
}

// ---------------- fallback edge kernel (gather, bf16 h) ----------------
__global__ __launch_bounds__(256) void k_edge_g(const float* __restrict__ edge_attr,
                                                const short* __restrict__ WtL,
                                                const float* __restrict__ ebL,
                                                const short* __restrict__ h_bn,
                                                const int* __restrict__ ei,
                                                const int* __restrict__ perm,
                                                float* __restrict__ agg) {
    __shared__ __align__(16) short sW[128 * 136];
    __shared__ __align__(16) char sU[64 * 132 * 4];
    __shared__ int sSrc[64], sDst[64], sEdge[64];
    short* sA = (short*)sU;
    float* sOut = (float*)sU;
    int tid = threadIdx.x;
    int tile = blockIdx.x;
    if (tid < 64) {
        int e = perm[tile * 64 + tid];
        sEdge[tid] = e;
        sSrc[tid] = ei[e];
        sDst[tid] = ei[EE + e];
    }
    const uint2* wg = (const uint2*)WtL;
    #pragma unroll
    for (int i = 0; i < 16; i++) {
        int idx = tid + i * 256;
        uint2 v = wg[idx];
        int n = idx >> 5, k4 = (idx & 31) << 2;
        *(uint2*)&sW[n * 136 + k4] = v;
    }
    __syncthreads();
    #pragma unroll
    for (int i = 0; i < 8; i++) {
        int idx = tid + i * 256;
        int r = idx >> 5, c4 = idx & 31;
        float4 v = ((const float4*)edge_attr)[sEdge[r] * 32 + c4];
        short4 b;
        b.x = f2bf(v.x); b.y = f2bf(v.y); b.z = f2bf(v.z); b.w = f2bf(v.w);
        *(short4*)&sA[r * 136 + (c4 << 2)] = b;
    }
    __syncthreads();
    int lane = tid & 63, wv = tid >> 6;
    int l15 = lane & 15, quad = lane >> 4;
    int r0 = wv * 16;
    f32x4 acc[8];
    #pragma unroll
    for (int i = 0; i < 8; i++) acc[i] = (f32x4){0.f, 0.f, 0.f, 0.f};
    #pragma unroll
    for (int kt = 0; kt < 4; kt++) {
        bf16x8 a = *(const bf16x8*)&sA[(r0 + l15) * 136 + kt * 32 + quad * 8];
        #pragma unroll
        for (int nt = 0; nt < 8; nt++) {
            bf16x8 b = *(const bf16x8*)&sW[(nt * 16 + l15) * 136 + kt * 32 + quad * 8];
            acc[nt] = __builtin_amdgcn_mfma_f32_16x16x32_bf16(a, b, acc[nt], 0, 0, 0);
        }
    }
    __syncthreads();
    #pragma unroll
    for (int nt = 0; nt < 8; nt++)
        #pragma unroll
        for (int reg = 0; reg < 4; reg++)
            sOut[(r0 + quad * 4 + reg) * 132 + nt * 16 + l15] = acc[nt][reg];
    __syncthreads();
    #pragma unroll
    for (int i = 0; i < 32; i++) {
        int idx = tid + i * 256;
        int r = idx >> 7, c = idx & 127;
        float hv = bf2f(*(const uint16_t*)&h_bn[(size_t)sSrc[r] * DDIM + c]);
        float v = sOut[r * 132 + c] + ebL[c] + hv;
        sOut[r * 132 + c] = fmaxf(v, 0.f);
    }
    __syncthreads();
    int c = tid & 127;
    int rbeg = (tid >> 7) * 32;
    float s = 0.f;
    int cur = sDst[rbeg];
    for (int r = rbeg; r < rbeg + 32; r++) {
        int d = sDst[r];
        if (d != cur) { atomicAdd(&agg[(size_t)cur * DDIM + c], s); s = 0.f; cur = d; }
        s += sOut[r * 132 + c];
    }
    atomicAdd(&agg[(size_t)cur * DDIM + c], s);
}

// ---------------- GEMM1 (N-split halves), bf16 h input, BN1 stats ----
__global__ __launch_bounds__(256) void k_gemm1z(const short* __restrict__ h_bn,
                                                const float* __restrict__ agg,
                                                const float* __restrict__ epsP, int l,
                                                const short* __restrict__ W1tL,
                                                float* __restrict__ zz,
                                                float* __restrict__ stats) {
    __shared__ __align__(16) short sB[128 * 136];  // 34816 B (half of W1)
    __shared__ __align__(16) short sA[64 * 136];   // 17408 B
    int tid = threadIdx.x;
    int tile = blockIdx.x;
    int half = blockIdx.y;
    float e1 = 1.f + epsP[l];
    const uint2* bg = (const uint2*)W1tL + (size_t)half * 128 * 32;
    #pragma unroll
    for (int i = 0; i < 16; i++) {
        int idx = tid + i * 256;
        uint2 v = bg[idx];
        int n = idx >> 5, k4 = (idx & 31) << 2;
        *(uint2*)&sB[n * 136 + k4] = v;
    }
    {
        int c4 = tid & 31;
        int c = c4 * 4;
        #pragma unroll
        for (int i = 0; i < 8; i++) {
            int idx = tid + i * 256;
            int r = idx >> 5;
            int gr = tile * 64 + r;
            short4 o = {0, 0, 0, 0};
            if (gr < NN) {
                ushort4 hb = ((const ushort4*)h_bn)[(size_t)gr * 32 + c4];
                float4 av = ((const float4*)agg)[(size_t)gr * 32 + c4];
                o.x = f2bf(e1 * bf2f(hb.x) + av.x);
                o.y = f2bf(e1 * bf2f(hb.y) + av.y);
                o.z = f2bf(e1 * bf2f(hb.z) + av.z);
                o.w = f2bf(e1 * bf2f(hb.w) + av.w);
            }
            *(short4*)&sA[r * 136 + c] = o;
        }
    }
    __syncthreads();
    int lane = tid & 63, wv = tid >> 6;
    int l15 = lane & 15, quad = lane >> 4;
    int r0 = wv * 16;
    f32x4 acc[8];
    #pragma unroll
    for (int i = 0; i < 8; i++) acc[i] = (f32x4){0.f, 0.f, 0.f, 0.f};
    #pragma unroll
    for (int kt = 0; kt < 4; kt++) {
        bf16x8 a = *(const bf16x8*)&sA[(r0 + l15) * 136 + kt * 32 + quad * 8];
        #pragma unroll
        for (int nt = 0; nt < 8; nt++) {
            bf16x8 b = *(const bf16x8*)&sB[(nt * 16 + l15) * 136 + kt * 32 + quad * 8];
            acc[nt] = __builtin_amdgcn_mfma_f32_16x16x32_bf16(a, b, acc[nt], 0, 0, 0);
        }
    }
    int grb = tile * 64 + r0 + quad * 4;
    #pragma unroll
    for (int nt = 0; nt < 8; nt++) {
        int col = half * 128 + nt * 16 + l15;
        float s = 0.f, s2 = 0.f;
        #pragma unroll
        for (int reg = 0; reg < 4; reg++) {
            int gr = grb + reg;
            float v = acc[nt][reg];
            s += v; s2 += v * v;
            if (gr < NN) zz[(size_t)gr * D2 + col] = v;
        }
        s += __shfl_xor(s, 16);  s += __shfl_xor(s, 32);
        s2 += __shfl_xor(s2, 16); s2 += __shfl_xor(s2, 32);
        if (quad == 0) {
            atomicAdd(&stats[col], s);
            atomicAdd(&stats[D2 + col], s2);
        }
    }
}

// ---------------- GEMM2 (N-split halves, K-split staging) with inline BN1 finalize + BN2 stats ----
__global__ __launch_bounds__(256) void k_gemm2s(const float* __restrict__ zz,
                                                const short* __restrict__ W2tL,
                                                const float* __restrict__ st1,
                                                const float* __restrict__ g1,
                                                const float* __restrict__ b1v,
                                                float* __restrict__ h_pre,
                                                float* __restrict__ stats) {
    __shared__ __align__(16) short sB[64 * 136];    // 17408 B
    __shared__ __align__(16) short sA[64 * 136];    // 17408 B
    __shared__ float sSc[256], sSh[256];
    int tid = threadIdx.x;
    int tile = blockIdx.x;
    int half = blockIdx.y;
    int lane = tid & 63, wv = tid >> 6;
    int l15 = lane & 15, quad = lane >> 4;
    int r0 = wv * 16;
    f32x4 acc[4];
    #pragma unroll
    for (int i = 0; i < 4; i++) acc[i] = (f32x4){0.f, 0.f, 0.f, 0.f};

    #pragma unroll 1
    for (int p = 0; p < 2; p++) {
        if (p == 0) {
            float inv_n = 1.f / (float)NN;
            float mu = st1[tid] * inv_n;
            float var = st1[256 + tid] * inv_n - mu * mu;
            float sc = g1[tid] * rsqrtf(var + BN_EPS);
            sSc[tid] = sc;
            sSh[tid] = b1v[tid] - mu * sc;
            const uint2* bg = (const uint2*)W2tL + (size_t)half * 64 * 64;
            #pragma unroll
            for (int i = 0; i < 8; i++) {
                int idx = tid + i * 256;
                int n = idx >> 5, k4q = idx & 31;
                uint2 v = bg[n * 64 + k4q];
                *(uint2*)&sB[n * 136 + k4q * 4] = v;
            }
            __syncthreads();
        } else {
            __syncthreads();
            const uint2* bg = (const uint2*)W2tL + (size_t)half * 64 * 64 + 32;
            #pragma unroll
            for (int i = 0; i < 8; i++) {
                int idx = tid + i * 256;
                int n = idx >> 5, k4q = idx & 31;
                uint2 v = bg[n * 64 + k4q];
                *(uint2*)&sB[n * 136 + k4q * 4] = v;
            }
        }
        {
            int c4q = tid & 31;
            int cb = p * 128 + c4q * 4;
            #pragma unroll
            for (int i = 0; i < 8; i++) {
                int r = (tid >> 5) + i * 8;
                int gr = tile * 64 + r;
                short4 o = {0, 0, 0, 0};
                if (gr < NN) {
                    float4 v = ((const float4*)zz)[(size_t)gr * 64 + p * 32 + c4q];
                    o.x = f2bf(fmaxf(v.x * sSc[cb + 0] + sSh[cb + 0], 0.f));
                    o.y = f2bf(fmaxf(v.y * sSc[cb + 1] + sSh[cb + 1], 0.f));
                    o.z = f2bf(fmaxf(v.z * sSc[cb + 2] + sSh[cb + 2], 0.f));
                    o.w = f2bf(fmaxf(v.w * sSc[cb + 3] + sSh[cb + 3], 0.f));
                }
                *(short4*)&sA[r * 136 + c4q * 4] = o;
            }
        }
        __syncthreads();
        #pragma unroll
        for (int kt = 0; kt < 4; kt++) {
            bf16x8 a = *(const bf16x8*)&sA[(r0 + l15) * 136 + kt * 32 + quad * 8];
            #pragma unroll
            for (int nt = 0; nt < 4; nt++) {
                bf16x8 b = *(const bf16x8*)&sB[(nt * 16 + l15) * 136 + kt * 32 + quad * 8];
                acc[nt] = __builtin_amdgcn_mfma_f32_16x16x32_bf16(a, b, acc[nt], 0, 0, 0);
            }
        }
    }
    int grb = tile * 64 + r0 + quad * 4;
    #pragma unroll
    for (int nt = 0; nt < 4; nt++) {
        int col = half * 64 + nt * 16 + l15;
        float s = 0.f, s2 = 0.f;
        #pragma unroll
        for (int reg = 0; reg < 4; reg++) {
            int gr = grb + reg;
            float v = acc[nt][reg];
            s += v; s2 += v * v;
            if (gr < NN) h_pre[(size_t)gr * DDIM + col] = v;
        }
        s += __shfl_xor(s, 16);  s += __shfl_xor(s, 32);
        s2 += __shfl_xor(s2, 16); s2 += __shfl_xor(s2, 32);
        if (quad == 0) {
            atomicAdd(&stats[col], s);
            atomicAdd(&stats[DDIM + col], s2);
        }
    }
}

// ---------------- outer BN, inline finalize; writes fp32 out OR bf16 h_bn ----------------
__global__ __launch_bounds__(256) void k_bn2(const float* __restrict__ h_pre,
                                             const float* __restrict__ st2,
                                             const float* __restrict__ g2,
                                             const float* __restrict__ b2v,
                                             int do_relu, float* __restrict__ dst,
                                             short* __restrict__ dst16, int write16) {
    int gid = blockIdx.x * 256 + threadIdx.x;
    int c0 = (gid & 31) << 2;
    float inv_n = 1.f / (float)NN;
    float4 v = ((const float4*)h_pre)[gid];
    float o[4];
    #pragma unroll
    for (int j = 0; j < 4; j++) {
        float mu = st2[c0 + j] * inv_n;
        float var = st2[128 + c0 + j] * inv_n - mu * mu;
        float sc = g2[c0 + j] * rsqrtf(var + BN_EPS);
        float sh = b2v[c0 + j] - mu * sc;
        float x = (&v.x)[j] * sc + sh;
        o[j] = do_relu ? fmaxf(x, 0.f) : x;
    }
    if (write16) {
        short4 ob;
        ob.x = f2bf(o[0]); ob.y = f2bf(o[1]); ob.z = f2bf(o[2]); ob.w = f2bf(o[3]);
        ((short4*)dst16)[gid] = ob;
    } else {
        ((float4*)dst)[gid] = make_float4(o[0], o[1], o[2], o[3]);
    }
}

extern "C" void kernel_launch(void* const* d_in, const int* in_sizes, int n_in,
                              void* d_out, int out_size, void* d_ws, size_t ws_size,
                              hipStream_t stream) {
    const int*   tok       = (const int*)d_in[0];
    const int*   ei        = (const int*)d_in[1];
    const float* edge_attr = (const float*)d_in[2];
    const float* emb       = (const float*)d_in[3];
    const float* eeW       = (const float*)d_in[4];
    const float* eeB       = (const float*)d_in[5];
    const float* W1        = (const float*)d_in[6];
    const float* bn1g      = (const float*)d_in[8];
    const float* bn1b      = (const float*)d_in[9];
    const float* W2        = (const float*)d_in[10];
    const float* epsP      = (const float*)d_in[12];
    const float* bng       = (const float*)d_in[13];
    const float* bnb       = (const float*)d_in[14];
    float* out = (float*)d_out;

    char* ws = (char*)d_ws;
    size_t off = 0;
    auto alloc = [&](size_t bytes) -> char* {
        off = (off + 511) & ~(size_t)511;
        char* p = ws + off;
        off += bytes;
        return p;
    };
    short* h_bn   = (short*)alloc((size_t)NN * DDIM * 2);          // bf16 layer input
    float* aggs   = (float*)alloc(((size_t)NN * DDIM + 768) * 4);  // agg + BN1 stats + BN2 stats
    float* agg    = aggs;
    float* stats1 = aggs + (size_t)NN * DDIM;
    float* stats2 = stats1 + 512;
    float* zz     = (float*)alloc((size_t)NN * D2 * 4);
    float* h_pre  = (float*)alloc((size_t)NN * DDIM * 4);
    int*   perm   = (int*)alloc((size_t)EE * 4);
    int*   rank   = (int*)alloc((size_t)EE * 4);
    int*   counts = (int*)alloc((size_t)NN * 4);
    int*   cursor = (int*)alloc((size_t)NN * 4);
    int*   srcs   = (int*)alloc((size_t)EE * 4);
    int*   dsts   = (int*)alloc((size_t)EE * 4);
    short* WtE    = (short*)alloc((size_t)NLAY * 128 * 128 * 2);
    short* W1t    = (short*)alloc((size_t)NLAY * 128 * 256 * 2);
    short* W2t    = (short*)alloc((size_t)NLAY * 256 * 128 * 2);
    short* ea_bf  = (short*)alloc((size_t)EE * DDIM * 2);          // 164 MB, allocated last
    bool big = (off <= ws_size);
    (void)in_sizes; (void)n_in; (void)out_size;

    hipMemsetAsync(counts, 0, (size_t)NN * 4, stream);
    k_prepw_all<<<960, 256, 0, stream>>>(eeW, W1, W2, WtE, W1t, W2t);
    k_embed_hist<<<2500, 256, 0, stream>>>(tok, emb, h_bn, ei, counts);
    k_scan<<<1, 1024, 0, stream>>>(counts, cursor);
    k_scatter<<<2500, 256, 0, stream>>>(ei, cursor, perm, rank);
    if (big) {
        k_permute2<<<EE * 32 / 256, 256, 0, stream>>>(edge_attr, ei, rank, ea_bf, srcs, dsts);
    }

    for (int l = 0; l < NLAY; l++) {
        hipMemsetAsync(aggs, 0, ((size_t)NN * DDIM + 768) * 4, stream);
        if (big) {
            k_edge3<<<EE / (64 * SUBS), 256, 0, stream>>>(ea_bf, srcs, dsts,
                                                          WtE + (size_t)l * 128 * 128,
                                                          eeB + (size_t)l * 128, h_bn, agg);
        } else {
            k_edge_g<<<EE / 64, 256, 0, stream>>>(edge_attr, WtE + (size_t)l * 128 * 128,
                                                  eeB + (size_t)l * 128, h_bn, ei, perm, agg);
        }
        k_gemm1z<<<dim3((NN + 63) / 64, 2), 256, 0, stream>>>(h_bn, agg, epsP, l,
                                                              W1t + (size_t)l * 128 * 256, zz, stats1);
        k_gemm2s<<<dim3((NN + 63) / 64, 2), 256, 0, stream>>>(zz, W2t + (size_t)l * 256 * 128,
                                                              stats1, bn1g + (size_t)l * 256,
                                                              bn1b + (size_t)l * 256, h_pre, stats2);
        int last = (l == NLAY - 1);
        k_bn2<<<2500, 256, 0, stream>>>(h_pre, stats2, bng + (size_t)l * 128,
                                        bnb + (size_t)l * 128,
                                        last ? 0 : 1, last ? out : nullptr,
                                        h_bn, last ? 0 : 1);
    }
}